// Round 9
// baseline (342.713 us; speedup 1.0000x reference)
//
#include <hip/hip_runtime.h>

#define TOBS  50
#define SDEC  100
#define HID   128
#define EMB   64
#define MD    256
#define M2N   112
#define NZ    16
#define ROWS  32
#define KPAD  140           // shorts; 70-dw row stride (R2/R7-proven low-conflict)
#define H1PAD 268

using bf16x8 = __attribute__((ext_vector_type(8))) short;
using f32x4  = __attribute__((ext_vector_type(4))) float;
using f32x2  = __attribute__((ext_vector_type(2))) float;

struct alignas(16) SMem {
  unsigned short h[2][ROWS * KPAD];      // 17920 B  h double buffer (bf16)
  unsigned int offsb[TOBS][ROWS];        //  6400 B  encoder offsets (bf16x2)
  union {
    float4 cl[512];                      //  8192 B  fused input consts
    unsigned short h1[ROWS * H1PAD];     // 17152 B  MLP hidden
    float outst[ROWS][SDEC][2];          // 25600 B  decoder output staging
  } u;
  uint4 b5f[64][5];                      //  5120 B  readout Wr frags (stride 5)
  float offlast[ROWS][2];
  float delta[ROWS][2];
};

__device__ __forceinline__ unsigned int rnd16(float x){
  return __builtin_bit_cast(unsigned int, x) + 0x8000u;
}
__device__ __forceinline__ unsigned int pkbf(float a, float b){
  return __builtin_amdgcn_perm(rnd16(b), rnd16(a), 0x07060302u);
}
__device__ __forceinline__ unsigned short bfs(float x){ return (unsigned short)(rnd16(x) >> 16); }
__device__ __forceinline__ float rcpf(float x){ return __builtin_amdgcn_rcpf(x); }
__device__ __forceinline__ bf16x8 pack8s(const float* p, float s){
  float4 a = *(const float4*)(p);
  float4 b = *(const float4*)(p + 4);
  uint4 u;
  u.x = pkbf(s*a.x, s*a.y); u.y = pkbf(s*a.z, s*a.w);
  u.z = pkbf(s*b.x, s*b.y); u.w = pkbf(s*b.z, s*b.w);
  return __builtin_bit_cast(bf16x8, u);
}
__device__ __forceinline__ bf16x8 pack8(const float* p){ return pack8s(p, 1.0f); }

// Pade [3/4] tanh: n = x*(105 + 10 x^2), d = 105 + 45 x^2 + x^4  (all pk-able)
#define PADE2(N_, D_, X_) do { \
  f32x2 s__ = (X_) * (X_); \
  D_ = s__ * (s__ + c45) + c105; \
  N_ = (X_) * (s__ * c10 + c105); \
} while(0)

// one LSTM output row-PAIR, exp-free rational form.
// acc holds pre-scaled preacts: i,f,o scaled 0.5 (sigma via tanh(u/2)), g scaled 1.
// sigma(u) = (d+n)/(2d);  tanh(g) = n/d;
// c' = [(d_f+n_f) c d_i d_g + (d_i+n_i) n_g d_f] / (2 d_f d_i d_g)
// h  = (d_o+n_o) n_c / (2 d_o d_c)
#define ELEM_P2(G, P) do { \
  f32x2 xi_, xf_, xg_, xo_; \
  xi_[0]=acc[G][0][2*(P)]; xi_[1]=acc[G][0][2*(P)+1]; \
  xf_[0]=acc[G][1][2*(P)]; xf_[1]=acc[G][1][2*(P)+1]; \
  xg_[0]=acc[G][2][2*(P)]; xg_[1]=acc[G][2][2*(P)+1]; \
  xo_[0]=acc[G][3][2*(P)]; xo_[1]=acc[G][3][2*(P)+1]; \
  f32x2 ni_, di_, nf_, df_, ng_, dg_; \
  PADE2(ni_, di_, xi_); PADE2(nf_, df_, xf_); PADE2(ng_, dg_, xg_); \
  f32x2 P2_ = di_ * dg_; \
  f32x2 DD_ = df_ * P2_; \
  f32x2 rD_; rD_[0]=rcpf(DD_[0]); rD_[1]=rcpf(DD_[1]); \
  f32x2 cp_; cp_[0]=cst[G][2*(P)]; cp_[1]=cst[G][2*(P)+1]; \
  f32x2 A_  = (df_ + nf_) * cp_; \
  f32x2 B_  = (di_ + ni_) * ng_; \
  f32x2 Nc_ = A_ * P2_ + B_ * df_; \
  f32x2 ch_ = Nc_ * (rD_ * halfv); \
  cst[G][2*(P)]=ch_[0]; cst[G][2*(P)+1]=ch_[1]; \
  f32x2 xc_; \
  xc_[0] = __builtin_fminf(__builtin_fmaxf(ch_[0], -4.0f), 4.0f); \
  xc_[1] = __builtin_fminf(__builtin_fmaxf(ch_[1], -4.0f), 4.0f); \
  f32x2 nc_, dc_, no_, do2_; \
  PADE2(nc_, dc_, xc_); PADE2(no_, do2_, xo_); \
  f32x2 QQ_ = dc_ * do2_; \
  f32x2 rQ_; rQ_[0]=rcpf(QQ_[0]); rQ_[1]=rcpf(QQ_[1]); \
  f32x2 E_  = (do2_ + no_) * nc_; \
  f32x2 hh_ = E_ * (rQ_ * halfv); \
  hn[((G)*16 + qd*4 + 2*(P))*KPAD + colj]     = bfs(hh_[0]); \
  hn[((G)*16 + qd*4 + 2*(P) + 1)*KPAD + colj] = bfs(hh_[1]); \
} while(0)

extern "C" __global__ void __launch_bounds__(512, 2)
seqgen(const float* __restrict__ obs,
       const float* __restrict__ We,    const float* __restrict__ be,
       const float* __restrict__ Wih_e, const float* __restrict__ Whh_e, const float* __restrict__ b_e,
       const float* __restrict__ Wm1,   const float* __restrict__ bm1,
       const float* __restrict__ Wm2,   const float* __restrict__ bm2,
       const float* __restrict__ Wd,    const float* __restrict__ bd,
       const float* __restrict__ Wih_d, const float* __restrict__ Whh_d, const float* __restrict__ b_d,
       const float* __restrict__ Wr,    const float* __restrict__ br,
       const float* __restrict__ z,     float* __restrict__ out)
{
  __shared__ SMem sm;
  const int tid  = threadIdx.x;
  const int lane = tid & 63;
  const int jq   = tid >> 6;        // wave = 16-col tile (0..7)
  const int cc   = lane & 15;
  const int qd   = lane >> 4;
  const bool q0  = (qd == 0);
  const int R0   = blockIdx.x * ROWS;
  const int colj = jq * 16 + cc;
  const unsigned int one_q0 = q0 ? 0x3F80u : 0u;
  const float sg4[4] = {0.5f, 0.5f, 1.0f, 0.5f};   // sigma-as-tanh(u/2) fold per gate
  const f32x2 halfv = {0.5f, 0.5f};
  const f32x2 c105  = {105.0f, 105.0f};
  const f32x2 c45   = {45.0f, 45.0f};
  const f32x2 c10   = {10.0f, 10.0f};

  // ---------------- prep ----------------
  for (int i = tid; i < TOBS * ROWS; i += 512){
    int t = i >> 5, row = i & 31;
    const float* ob = obs + (size_t)(R0 + row) * (TOBS * 2) + t * 2;
    float o0 = ob[0], o1 = ob[1];
    if (t){ o0 -= ob[-2]; o1 -= ob[-1]; }
    sm.offsb[t][row] = pkbf(o0, o1);
    if (t == TOBS - 1){ sm.offlast[row][0] = o0; sm.offlast[row][1] = o1; }
  }
  for (int i = tid; i < ROWS * KPAD / 2; i += 512)
    ((unsigned int*)&sm.h[0][0])[i] = 0u;
  {
    const float* wr = Wih_e + tid * EMB;
    float w0 = 0.f, w1 = 0.f, bb = b_e[tid];
    for (int e = 0; e < EMB; ++e){
      float w = wr[e];
      w0 += w * We[e*2]; w1 += w * We[e*2+1]; bb += w * be[e];
    }
    sm.u.cl[tid] = make_float4(bb, w0, w1, 0.f);
  }
  __syncthreads();

  // input/bias B-frags {s*w0, s*w1, s*bc} at k=0,1,2 (qd==0 lanes)
  bf16x8 b5x[4];
  #pragma unroll
  for (int g = 0; g < 4; ++g){
    float4 v = sm.u.cl[g*128 + colj];
    float s = sg4[g];
    uint4 w;
    w.x = q0 ? pkbf(s*v.y, s*v.z) : 0u;
    w.y = q0 ? (rnd16(s*v.x) >> 16) : 0u;
    w.z = 0u; w.w = 0u;
    b5x[g] = __builtin_bit_cast(bf16x8, w);
  }
  // encoder Whh in registers, pre-scaled per gate
  bf16x8 bfr[4][4];
  #pragma unroll
  for (int kt = 0; kt < 4; ++kt)
    #pragma unroll
    for (int g = 0; g < 4; ++g)
      bfr[g][kt] = pack8s(Whh_e + (size_t)(g*128 + colj) * HID + kt*32 + qd*8, sg4[g]);

  const f32x4 zz4 = {0.f, 0.f, 0.f, 0.f};
  f32x4 acc[2][4];
  float cst[2][4];
  #pragma unroll
  for (int G = 0; G < 2; ++G)
    #pragma unroll
    for (int r = 0; r < 4; ++r) cst[G][r] = 0.f;

  // ================= encoder: 50 steps, ONE barrier/step =================
  // structure: G0 MFMA chain -> [G1 MFMA chain interleaved with G0 ELEM] -> G1 ELEM
  unsigned int po0 = sm.offsb[0][cc];
  unsigned int po1 = sm.offsb[0][16 + cc];
  #pragma unroll 1
  for (int t = 0; t < TOBS; ++t){
    const int par = t & 1;
    bf16x8 af0[4], af1[4];
    #pragma unroll
    for (int kt = 0; kt < 4; ++kt)
      af0[kt] = *(const bf16x8*)&sm.h[par][cc*KPAD + kt*32 + qd*8];
    {
      uint4 a5i; a5i.x = q0 ? po0 : 0u; a5i.y = one_q0; a5i.z = 0u; a5i.w = 0u;
      bf16x8 af5 = __builtin_bit_cast(bf16x8, a5i);
      #pragma unroll
      for (int g = 0; g < 4; ++g)
        acc[0][g] = __builtin_amdgcn_mfma_f32_16x16x32_bf16(af5, b5x[g], zz4, 0,0,0);
    }
    #pragma unroll
    for (int kt = 0; kt < 4; ++kt)
      #pragma unroll
      for (int g = 0; g < 4; ++g)
        acc[0][g] = __builtin_amdgcn_mfma_f32_16x16x32_bf16(af0[kt], bfr[g][kt], acc[0][g], 0,0,0);
    #pragma unroll
    for (int kt = 0; kt < 4; ++kt)
      af1[kt] = *(const bf16x8*)&sm.h[par][(16 + cc)*KPAD + kt*32 + qd*8];
    {
      uint4 a5i; a5i.x = q0 ? po1 : 0u; a5i.y = one_q0; a5i.z = 0u; a5i.w = 0u;
      bf16x8 af5 = __builtin_bit_cast(bf16x8, a5i);
      #pragma unroll
      for (int g = 0; g < 4; ++g)
        acc[1][g] = __builtin_amdgcn_mfma_f32_16x16x32_bf16(af5, b5x[g], zz4, 0,0,0);
    }
    // prefetch next step's offsets (latency hidden under MFMA/ELEM region)
    {
      int tn = (t + 1 < TOBS) ? t + 1 : t;
      po0 = sm.offsb[tn][cc];
      po1 = sm.offsb[tn][16 + cc];
    }
    unsigned short* hn = &sm.h[par ^ 1][0];
    // interleave: 8 G1-MFMAs then one G0 ELEM pair
    #pragma unroll
    for (int kt = 0; kt < 2; ++kt)
      #pragma unroll
      for (int g = 0; g < 4; ++g)
        acc[1][g] = __builtin_amdgcn_mfma_f32_16x16x32_bf16(af1[kt], bfr[g][kt], acc[1][g], 0,0,0);
    ELEM_P2(0, 0);
    #pragma unroll
    for (int kt = 2; kt < 4; ++kt)
      #pragma unroll
      for (int g = 0; g < 4; ++g)
        acc[1][g] = __builtin_amdgcn_mfma_f32_16x16x32_bf16(af1[kt], bfr[g][kt], acc[1][g], 0,0,0);
    ELEM_P2(0, 1);
    ELEM_P2(1, 0); ELEM_P2(1, 1);
    __syncthreads();
  }
  // hF in sm.h[0]

  // ================= MLP =================
  {
    bf16x8 af[2][4];
    #pragma unroll
    for (int G = 0; G < 2; ++G)
      #pragma unroll
      for (int kt = 0; kt < 4; ++kt)
        af[G][kt] = *(const bf16x8*)&sm.h[0][(G*16 + cc)*KPAD + kt*32 + qd*8];
    f32x4 a1[2][2];
    #pragma unroll
    for (int t2 = 0; t2 < 2; ++t2){
      const int n = jq*32 + t2*16 + cc;
      float b = bm1[n];
      #pragma unroll
      for (int G = 0; G < 2; ++G){ a1[t2][G][0]=b; a1[t2][G][1]=b; a1[t2][G][2]=b; a1[t2][G][3]=b; }
      #pragma unroll
      for (int kt = 0; kt < 4; ++kt){
        bf16x8 wb = pack8(Wm1 + (size_t)n * HID + kt*32 + qd*8);
        a1[t2][0] = __builtin_amdgcn_mfma_f32_16x16x32_bf16(af[0][kt], wb, a1[t2][0], 0,0,0);
        a1[t2][1] = __builtin_amdgcn_mfma_f32_16x16x32_bf16(af[1][kt], wb, a1[t2][1], 0,0,0);
      }
    }
    __syncthreads();
    #pragma unroll
    for (int t2 = 0; t2 < 2; ++t2)
      #pragma unroll
      for (int G = 0; G < 2; ++G)
        #pragma unroll
        for (int r = 0; r < 4; ++r){
          float v = a1[t2][G][r]; v = v > 0.f ? v : 0.f;
          sm.u.h1[(G*16 + qd*4 + r)*H1PAD + jq*32 + t2*16 + cc] = bfs(v);
        }
  }
  __syncthreads();
  {
    bf16x8 af2[2][8];
    #pragma unroll
    for (int G = 0; G < 2; ++G)
      #pragma unroll
      for (int kt = 0; kt < 8; ++kt)
        af2[G][kt] = *(const bf16x8*)&sm.u.h1[(G*16 + cc)*H1PAD + kt*32 + qd*8];
    if (jq < 7){
      const int n2 = jq*16 + cc;
      float b = bm2[n2];
      f32x4 a2[2];
      #pragma unroll
      for (int G = 0; G < 2; ++G){ a2[G][0]=b; a2[G][1]=b; a2[G][2]=b; a2[G][3]=b; }
      #pragma unroll
      for (int kt = 0; kt < 8; ++kt){
        bf16x8 wb = pack8(Wm2 + (size_t)n2 * MD + kt*32 + qd*8);
        a2[0] = __builtin_amdgcn_mfma_f32_16x16x32_bf16(af2[0][kt], wb, a2[0], 0,0,0);
        a2[1] = __builtin_amdgcn_mfma_f32_16x16x32_bf16(af2[1][kt], wb, a2[1], 0,0,0);
      }
      #pragma unroll
      for (int G = 0; G < 2; ++G)
        #pragma unroll
        for (int r = 0; r < 4; ++r){
          float v = a2[G][r]; v = v > 0.f ? v : 0.f;
          sm.h[0][(G*16 + qd*4 + r)*KPAD + jq*16 + cc] = bfs(v);
        }
    }
    {
      int row = tid >> 4, nz = tid & 15;
      sm.h[0][row*KPAD + M2N + nz] = bfs(z[(size_t)(R0 + row)*NZ + nz]);
    }
  }
  __syncthreads();   // dh complete in h[0]

  // ================= decoder prep =================
  {
    const float* wr = Wih_d + tid * EMB;
    float w0 = 0.f, w1 = 0.f, bb = b_d[tid];
    for (int e = 0; e < EMB; ++e){
      float w = wr[e];
      w0 += w * Wd[e*2]; w1 += w * Wd[e*2+1]; bb += w * bd[e];
    }
    sm.u.cl[tid] = make_float4(bb, w0, w1, 0.f);
  }
  const float br0 = br[0], br1 = br[1];
  const float brc = (cc == 0) ? br0 : br1;
  if (jq == 1){   // readout Wr fragments + step-0 delta (one-time)
    uint4 bq[4];
    #pragma unroll
    for (int kt = 0; kt < 4; ++kt){
      bf16x8 f = pack8(Wr + (size_t)(cc & 1)*HID + kt*32 + qd*8);
      uint4 uu = __builtin_bit_cast(uint4, f);
      if (cc >= 2){ uu.x = 0u; uu.y = 0u; uu.z = 0u; uu.w = 0u; }
      bq[kt] = uu;
      sm.b5f[lane][kt] = uu;
    }
    #pragma unroll
    for (int G = 0; G < 2; ++G){
      bf16x8 afd[4];
      #pragma unroll
      for (int kt = 0; kt < 4; ++kt)
        afd[kt] = *(const bf16x8*)&sm.h[0][(G*16 + cc)*KPAD + kt*32 + qd*8];
      f32x4 a5 = zz4;
      #pragma unroll
      for (int kt = 0; kt < 4; ++kt)
        a5 = __builtin_amdgcn_mfma_f32_16x16x32_bf16(afd[kt], __builtin_bit_cast(bf16x8, bq[kt]), a5, 0,0,0);
      if (cc < 2){
        #pragma unroll
        for (int r = 0; r < 4; ++r){
          int row = G*16 + qd*4 + r;
          sm.delta[row][cc] = sm.offlast[row][cc] - (a5[r] + brc);
        }
      }
    }
  }
  __syncthreads();

  // feedback-folded decoder consts (pre-scaled): bfr' = s_g*(Whh_d + u0(x)Wr0 + u1(x)Wr1)
  float w0g[4], w1g[4];
  f32x4 civ[4];                 // steady-state C-init: splat(s_g * bc'_g)
  #pragma unroll
  for (int g = 0; g < 4; ++g){
    float4 v = sm.u.cl[g*128 + colj];
    w0g[g] = v.y; w1g[g] = v.z;
    float s = sg4[g];
    float bcp = v.x + v.y*br0 + v.z*br1;
    float ci = s * bcp;
    civ[g][0] = ci; civ[g][1] = ci; civ[g][2] = ci; civ[g][3] = ci;
    uint4 w;
    w.x = q0 ? pkbf(s*v.y, s*v.z) : 0u;
    w.y = q0 ? (rnd16(s*bcp) >> 16) : 0u;
    w.z = 0u; w.w = 0u;
    b5x[g] = __builtin_bit_cast(bf16x8, w);
  }
  #pragma unroll
  for (int kt = 0; kt < 4; ++kt){
    const int kb = kt*32 + qd*8;
    float4 wa = *(const float4*)(Wr + kb),       wb2 = *(const float4*)(Wr + kb + 4);
    float4 va = *(const float4*)(Wr + HID + kb), vb2 = *(const float4*)(Wr + HID + kb + 4);
    #pragma unroll
    for (int g = 0; g < 4; ++g){
      const float* pp = Whh_d + (size_t)(g*128 + colj) * HID + kb;
      float4 fa = *(const float4*)pp, fb = *(const float4*)(pp + 4);
      float s = sg4[g];
      uint4 uu;
      uu.x = pkbf(s*(fa.x + w0g[g]*wa.x  + w1g[g]*va.x),  s*(fa.y + w0g[g]*wa.y  + w1g[g]*va.y));
      uu.y = pkbf(s*(fa.z + w0g[g]*wa.z  + w1g[g]*va.z),  s*(fa.w + w0g[g]*wa.w  + w1g[g]*va.w));
      uu.z = pkbf(s*(fb.x + w0g[g]*wb2.x + w1g[g]*vb2.x), s*(fb.y + w0g[g]*wb2.y + w1g[g]*vb2.y));
      uu.w = pkbf(s*(fb.z + w0g[g]*wb2.z + w1g[g]*vb2.z), s*(fb.w + w0g[g]*wb2.w + w1g[g]*vb2.w));
      bfr[g][kt] = __builtin_bit_cast(bf16x8, uu);
    }
  }
  // step-0 delta A-frags
  uint4 c5; c5.x = 0u; c5.y = one_q0; c5.z = 0u; c5.w = 0u;
  float2 dv0 = *(const float2*)&sm.delta[cc][0];
  float2 dv1 = *(const float2*)&sm.delta[16 + cc][0];
  uint4 d0u = c5; d0u.x = q0 ? pkbf(dv0.x, dv0.y) : 0u;
  uint4 d1u = c5; d1u.x = q0 ? pkbf(dv1.x, dv1.y) : 0u;
  const bf16x8 af5d0 = __builtin_bit_cast(bf16x8, d0u);
  const bf16x8 af5d1 = __builtin_bit_cast(bf16x8, d1u);

  // readout ownership: jq==1 -> G0 rows, jq==3 -> G1 rows
  const int Gown = (jq == 3) ? 1 : 0;
  float cum[4] = {0.f,0.f,0.f,0.f};
  if ((jq == 1 || jq == 3) && cc < 2){
    #pragma unroll
    for (int r = 0; r < 4; ++r)
      cum[r] = obs[(size_t)(R0 + Gown*16 + qd*4 + r)*(TOBS*2) + (TOBS-1)*2 + cc];
  }
  #pragma unroll
  for (int G = 0; G < 2; ++G)
    #pragma unroll
    for (int r = 0; r < 4; ++r) cst[G][r] = 0.f;
  __syncthreads();   // cl reads done; outst region now writable

  // ================= decoder: 100 steps, ONE barrier/step, NO global ops =================
  #pragma unroll 1
  for (int s = 0; s < SDEC; ++s){
    const int par = s & 1;
    bf16x8 af0[4], af1[4];
    #pragma unroll
    for (int kt = 0; kt < 4; ++kt)
      af0[kt] = *(const bf16x8*)&sm.h[par][cc*KPAD + kt*32 + qd*8];
    // G0 chain (kt0 carries the C-init; s==0 adds the delta-MFMA)
    if (s == 0){
      #pragma unroll
      for (int g = 0; g < 4; ++g){
        acc[0][g] = __builtin_amdgcn_mfma_f32_16x16x32_bf16(af5d0, b5x[g], zz4, 0,0,0);
        acc[0][g] = __builtin_amdgcn_mfma_f32_16x16x32_bf16(af0[0], bfr[g][0], acc[0][g], 0,0,0);
      }
    } else {
      #pragma unroll
      for (int g = 0; g < 4; ++g)
        acc[0][g] = __builtin_amdgcn_mfma_f32_16x16x32_bf16(af0[0], bfr[g][0], civ[g], 0,0,0);
    }
    #pragma unroll
    for (int kt = 1; kt < 4; ++kt)
      #pragma unroll
      for (int g = 0; g < 4; ++g)
        acc[0][g] = __builtin_amdgcn_mfma_f32_16x16x32_bf16(af0[kt], bfr[g][kt], acc[0][g], 0,0,0);
    #pragma unroll
    for (int kt = 0; kt < 4; ++kt)
      af1[kt] = *(const bf16x8*)&sm.h[par][(16 + cc)*KPAD + kt*32 + qd*8];
    // readout G0 (wave jq==1 only)
    if (jq == 1 && s > 0){
      f32x4 a5 = {brc, brc, brc, brc};
      #pragma unroll
      for (int kt = 0; kt < 4; ++kt)
        a5 = __builtin_amdgcn_mfma_f32_16x16x32_bf16(af0[kt],
               __builtin_bit_cast(bf16x8, sm.b5f[lane][kt]), a5, 0,0,0);
      if (cc < 2){
        #pragma unroll
        for (int r = 0; r < 4; ++r){
          cum[r] += a5[r];
          sm.u.outst[qd*4 + r][s-1][cc] = cum[r];
        }
      }
    }
    // G1 chain interleaved with G0 ELEM pairs
    unsigned short* hn = &sm.h[par ^ 1][0];
    if (s == 0){
      #pragma unroll
      for (int g = 0; g < 4; ++g){
        acc[1][g] = __builtin_amdgcn_mfma_f32_16x16x32_bf16(af5d1, b5x[g], zz4, 0,0,0);
        acc[1][g] = __builtin_amdgcn_mfma_f32_16x16x32_bf16(af1[0], bfr[g][0], acc[1][g], 0,0,0);
      }
    } else {
      #pragma unroll
      for (int g = 0; g < 4; ++g)
        acc[1][g] = __builtin_amdgcn_mfma_f32_16x16x32_bf16(af1[0], bfr[g][0], civ[g], 0,0,0);
    }
    #pragma unroll
    for (int g = 0; g < 4; ++g)
      acc[1][g] = __builtin_amdgcn_mfma_f32_16x16x32_bf16(af1[1], bfr[g][1], acc[1][g], 0,0,0);
    ELEM_P2(0, 0);
    #pragma unroll
    for (int kt = 2; kt < 4; ++kt)
      #pragma unroll
      for (int g = 0; g < 4; ++g)
        acc[1][g] = __builtin_amdgcn_mfma_f32_16x16x32_bf16(af1[kt], bfr[g][kt], acc[1][g], 0,0,0);
    ELEM_P2(0, 1);
    // readout G1 (wave jq==3 only) — matrix work overlapping others' ELEM
    if (jq == 3 && s > 0){
      f32x4 a5 = {brc, brc, brc, brc};
      #pragma unroll
      for (int kt = 0; kt < 4; ++kt)
        a5 = __builtin_amdgcn_mfma_f32_16x16x32_bf16(af1[kt],
               __builtin_bit_cast(bf16x8, sm.b5f[lane][kt]), a5, 0,0,0);
      if (cc < 2){
        #pragma unroll
        for (int r = 0; r < 4; ++r){
          cum[r] += a5[r];
          sm.u.outst[16 + qd*4 + r][s-1][cc] = cum[r];
        }
      }
    }
    ELEM_P2(1, 0); ELEM_P2(1, 1);
    __syncthreads();
  }

  // epilogue: pred[S-1] from h[0] (= h_{S-1}); split across jq==1 / jq==3
  if (jq == 1 || jq == 3){
    bf16x8 af[4];
    #pragma unroll
    for (int kt = 0; kt < 4; ++kt)
      af[kt] = *(const bf16x8*)&sm.h[0][(Gown*16 + cc)*KPAD + kt*32 + qd*8];
    f32x4 a5 = {brc, brc, brc, brc};
    #pragma unroll
    for (int kt = 0; kt < 4; ++kt)
      a5 = __builtin_amdgcn_mfma_f32_16x16x32_bf16(af[kt],
             __builtin_bit_cast(bf16x8, sm.b5f[lane][kt]), a5, 0,0,0);
    if (cc < 2){
      #pragma unroll
      for (int r = 0; r < 4; ++r)
        sm.u.outst[Gown*16 + qd*4 + r][SDEC-1][cc] = cum[r] + a5[r];
    }
  }
  __syncthreads();

  // bulk write: LDS staging -> HBM, fully coalesced float2
  {
    const float2* src = (const float2*)&sm.u.outst[0][0][0];
    float2* dst = (float2*)(out + (size_t)R0 * SDEC * 2);
    for (int i = tid; i < ROWS * SDEC; i += 512)
      dst[i] = src[i];
  }
}

extern "C" void kernel_launch(void* const* d_in, const int* in_sizes, int n_in,
                              void* d_out, int out_size, void* d_ws, size_t ws_size,
                              hipStream_t stream) {
  (void)in_sizes; (void)n_in; (void)d_ws; (void)ws_size; (void)out_size;
  const float* obs   = (const float*)d_in[0];
  // d_in[1] = num_steps (100), compile-time constant here
  const float* We    = (const float*)d_in[2];
  const float* be    = (const float*)d_in[3];
  const float* Wih_e = (const float*)d_in[4];
  const float* Whh_e = (const float*)d_in[5];
  const float* b_e   = (const float*)d_in[6];
  const float* Wm1   = (const float*)d_in[7];
  const float* bm1   = (const float*)d_in[8];
  const float* Wm2   = (const float*)d_in[9];
  const float* bm2   = (const float*)d_in[10];
  const float* Wd    = (const float*)d_in[11];
  const float* bd    = (const float*)d_in[12];
  const float* Wih_d = (const float*)d_in[13];
  const float* Whh_d = (const float*)d_in[14];
  const float* b_d   = (const float*)d_in[15];
  const float* Wr    = (const float*)d_in[16];
  const float* br    = (const float*)d_in[17];
  const float* zz    = (const float*)d_in[18];
  hipLaunchKernelGGL(seqgen, dim3(8192 / ROWS), dim3(512), 0, stream,
                     obs, We, be, Wih_e, Whh_e, b_e, Wm1, bm1, Wm2, bm2,
                     Wd, bd, Wih_d, Whh_d, b_d, Wr, br, zz, (float*)d_out);
}

// Round 10
// 317.781 us; speedup vs baseline: 1.0785x; 1.0785x over previous
//
#include <hip/hip_runtime.h>

#define TOBS  50
#define SDEC  100
#define HID   128
#define EMB   64
#define MD    256
#define M2N   112
#define NZ    16
#define ROWS  32
#define KPAD  140           // shorts; 70-dw row stride (R2/R7-proven low-conflict)
#define H1PAD 268
#define L2E   1.4426950408889634f
#define TL2E  2.8853900817779268f

using bf16x8 = __attribute__((ext_vector_type(8))) short;
using f32x4  = __attribute__((ext_vector_type(4))) float;
using f32x2  = __attribute__((ext_vector_type(2))) float;

struct alignas(16) SMem {
  unsigned short h[2][ROWS * KPAD];      // 17920 B  h double buffer (bf16)
  unsigned int offsb[TOBS][ROWS];        //  6400 B  encoder offsets (bf16x2)
  union {
    float4 cl[512];                      //  8192 B  fused input consts
    unsigned short h1[ROWS * H1PAD];     // 17152 B  MLP hidden
    float outst[ROWS][SDEC][2];          // 25600 B  decoder output staging
  } u;
  uint4 b5f[64][5];                      //  5120 B  readout Wr frags (stride 5)
  float offlast[ROWS][2];
  float delta[ROWS][2];
};

__device__ __forceinline__ unsigned int rnd16(float x){
  return __builtin_bit_cast(unsigned int, x) + 0x8000u;
}
__device__ __forceinline__ unsigned int pkbf(float a, float b){
  return __builtin_amdgcn_perm(rnd16(b), rnd16(a), 0x07060302u);
}
__device__ __forceinline__ unsigned short bfs(float x){ return (unsigned short)(rnd16(x) >> 16); }
__device__ __forceinline__ float rcpf(float x){ return __builtin_amdgcn_rcpf(x); }
__device__ __forceinline__ float ex2(float x){ return __builtin_amdgcn_exp2f(x); }
__device__ __forceinline__ bf16x8 pack8s(const float* p, float s){
  float4 a = *(const float4*)(p);
  float4 b = *(const float4*)(p + 4);
  uint4 u;
  u.x = pkbf(s*a.x, s*a.y); u.y = pkbf(s*a.z, s*a.w);
  u.z = pkbf(s*b.x, s*b.y); u.w = pkbf(s*b.z, s*b.w);
  return __builtin_bit_cast(bf16x8, u);
}
__device__ __forceinline__ bf16x8 pack8(const float* p){ return pack8s(p, 1.0f); }

// one LSTM output row-PAIR: consumes acc[G][0..3][2P..2P+1], updates cst, writes h.
// Non-trans algebra in f32x2 -> v_pk_{add,mul,fma}_f32; trans (exp2/rcp) scalar.
#define ELEM_P2(G, P) do { \
  f32x2 ei_, ef_, eg_, eo_; \
  ei_[0]=ex2(acc[G][0][2*(P)]); ei_[1]=ex2(acc[G][0][2*(P)+1]); \
  ef_[0]=ex2(acc[G][1][2*(P)]); ef_[1]=ex2(acc[G][1][2*(P)+1]); \
  eg_[0]=ex2(acc[G][2][2*(P)]); eg_[1]=ex2(acc[G][2][2*(P)+1]); \
  eo_[0]=ex2(acc[G][3][2*(P)]); eo_[1]=ex2(acc[G][3][2*(P)+1]); \
  f32x2 a1_ = onev + ef_, a2_ = onev + ei_, a3_ = onev + eg_; \
  f32x2 Pp_ = a2_ * a3_; \
  f32x2 D_  = a1_ * Pp_; \
  f32x2 rD_; rD_[0]=rcpf(D_[0]); rD_[1]=rcpf(D_[1]); \
  f32x2 cp_; cp_[0]=cst[G][2*(P)]; cp_[1]=cst[G][2*(P)+1]; \
  f32x2 N_  = cp_ * Pp_ + (onev - eg_) * a1_; \
  f32x2 cn_ = N_ * rD_; \
  cst[G][2*(P)]=cn_[0]; cst[G][2*(P)+1]=cn_[1]; \
  f32x2 ag_ = cn_ * mtl2e; \
  f32x2 em_; em_[0]=ex2(ag_[0]); em_[1]=ex2(ag_[1]); \
  f32x2 Q_  = (onev + eo_) * (onev + em_); \
  f32x2 rQ_; rQ_[0]=rcpf(Q_[0]); rQ_[1]=rcpf(Q_[1]); \
  f32x2 hh_ = (onev - em_) * rQ_; \
  hn[((G)*16 + qd*4 + 2*(P))*KPAD + colj]     = bfs(hh_[0]); \
  hn[((G)*16 + qd*4 + 2*(P) + 1)*KPAD + colj] = bfs(hh_[1]); \
} while(0)

extern "C" __global__ void __launch_bounds__(512, 2)
seqgen(const float* __restrict__ obs,
       const float* __restrict__ We,    const float* __restrict__ be,
       const float* __restrict__ Wih_e, const float* __restrict__ Whh_e, const float* __restrict__ b_e,
       const float* __restrict__ Wm1,   const float* __restrict__ bm1,
       const float* __restrict__ Wm2,   const float* __restrict__ bm2,
       const float* __restrict__ Wd,    const float* __restrict__ bd,
       const float* __restrict__ Wih_d, const float* __restrict__ Whh_d, const float* __restrict__ b_d,
       const float* __restrict__ Wr,    const float* __restrict__ br,
       const float* __restrict__ z,     float* __restrict__ out)
{
  __shared__ SMem sm;
  const int tid  = threadIdx.x;
  const int lane = tid & 63;
  const int jq   = tid >> 6;        // wave = 16-col tile (0..7)
  const int cc   = lane & 15;
  const int qd   = lane >> 4;
  const bool q0  = (qd == 0);
  const int R0   = blockIdx.x * ROWS;
  const int colj = jq * 16 + cc;
  const unsigned int one_q0 = q0 ? 0x3F80u : 0u;
  const float sg4[4] = {-L2E, -L2E, -TL2E, -L2E};   // exp2 scale folded per gate
  const f32x2 onev  = {1.0f, 1.0f};
  const f32x2 mtl2e = {-TL2E, -TL2E};

  // ---------------- prep ----------------
  for (int i = tid; i < TOBS * ROWS; i += 512){
    int t = i >> 5, row = i & 31;
    const float* ob = obs + (size_t)(R0 + row) * (TOBS * 2) + t * 2;
    float o0 = ob[0], o1 = ob[1];
    if (t){ o0 -= ob[-2]; o1 -= ob[-1]; }
    sm.offsb[t][row] = pkbf(o0, o1);
    if (t == TOBS - 1){ sm.offlast[row][0] = o0; sm.offlast[row][1] = o1; }
  }
  for (int i = tid; i < ROWS * KPAD / 2; i += 512)
    ((unsigned int*)&sm.h[0][0])[i] = 0u;
  {
    const float* wr = Wih_e + tid * EMB;
    float w0 = 0.f, w1 = 0.f, bb = b_e[tid];
    for (int e = 0; e < EMB; ++e){
      float w = wr[e];
      w0 += w * We[e*2]; w1 += w * We[e*2+1]; bb += w * be[e];
    }
    sm.u.cl[tid] = make_float4(bb, w0, w1, 0.f);
  }
  __syncthreads();

  // input/bias B-frags {s*w0, s*w1, s*bc} at k=0,1,2 (qd==0 lanes)
  bf16x8 b5x[4];
  #pragma unroll
  for (int g = 0; g < 4; ++g){
    float4 v = sm.u.cl[g*128 + colj];
    float s = sg4[g];
    uint4 w;
    w.x = q0 ? pkbf(s*v.y, s*v.z) : 0u;
    w.y = q0 ? (rnd16(s*v.x) >> 16) : 0u;
    w.z = 0u; w.w = 0u;
    b5x[g] = __builtin_bit_cast(bf16x8, w);
  }
  // encoder Whh in registers, pre-scaled per gate
  bf16x8 bfr[4][4];
  #pragma unroll
  for (int kt = 0; kt < 4; ++kt)
    #pragma unroll
    for (int g = 0; g < 4; ++g)
      bfr[g][kt] = pack8s(Whh_e + (size_t)(g*128 + colj) * HID + kt*32 + qd*8, sg4[g]);

  const f32x4 zz4 = {0.f, 0.f, 0.f, 0.f};
  f32x4 acc[2][4];
  float cst[2][4];
  #pragma unroll
  for (int G = 0; G < 2; ++G)
    #pragma unroll
    for (int r = 0; r < 4; ++r) cst[G][r] = 0.f;

  // ================= encoder: 50 steps, ONE barrier/step =================
  // structure: G0 MFMA chain -> [G1 MFMA chain interleaved with G0 ELEM] -> G1 ELEM
  unsigned int po0 = sm.offsb[0][cc];
  unsigned int po1 = sm.offsb[0][16 + cc];
  #pragma unroll 1
  for (int t = 0; t < TOBS; ++t){
    const int par = t & 1;
    bf16x8 af0[4], af1[4];
    #pragma unroll
    for (int kt = 0; kt < 4; ++kt)
      af0[kt] = *(const bf16x8*)&sm.h[par][cc*KPAD + kt*32 + qd*8];
    {
      uint4 a5i; a5i.x = q0 ? po0 : 0u; a5i.y = one_q0; a5i.z = 0u; a5i.w = 0u;
      bf16x8 af5 = __builtin_bit_cast(bf16x8, a5i);
      #pragma unroll
      for (int g = 0; g < 4; ++g)
        acc[0][g] = __builtin_amdgcn_mfma_f32_16x16x32_bf16(af5, b5x[g], zz4, 0,0,0);
    }
    #pragma unroll
    for (int kt = 0; kt < 4; ++kt)
      #pragma unroll
      for (int g = 0; g < 4; ++g)
        acc[0][g] = __builtin_amdgcn_mfma_f32_16x16x32_bf16(af0[kt], bfr[g][kt], acc[0][g], 0,0,0);
    #pragma unroll
    for (int kt = 0; kt < 4; ++kt)
      af1[kt] = *(const bf16x8*)&sm.h[par][(16 + cc)*KPAD + kt*32 + qd*8];
    {
      uint4 a5i; a5i.x = q0 ? po1 : 0u; a5i.y = one_q0; a5i.z = 0u; a5i.w = 0u;
      bf16x8 af5 = __builtin_bit_cast(bf16x8, a5i);
      #pragma unroll
      for (int g = 0; g < 4; ++g)
        acc[1][g] = __builtin_amdgcn_mfma_f32_16x16x32_bf16(af5, b5x[g], zz4, 0,0,0);
    }
    // prefetch next step's offsets (latency hidden under MFMA/ELEM region)
    {
      int tn = (t + 1 < TOBS) ? t + 1 : t;
      po0 = sm.offsb[tn][cc];
      po1 = sm.offsb[tn][16 + cc];
    }
    unsigned short* hn = &sm.h[par ^ 1][0];
    // interleave: 8 G1-MFMAs then one G0 ELEM pair
    #pragma unroll
    for (int kt = 0; kt < 2; ++kt)
      #pragma unroll
      for (int g = 0; g < 4; ++g)
        acc[1][g] = __builtin_amdgcn_mfma_f32_16x16x32_bf16(af1[kt], bfr[g][kt], acc[1][g], 0,0,0);
    ELEM_P2(0, 0);
    #pragma unroll
    for (int kt = 2; kt < 4; ++kt)
      #pragma unroll
      for (int g = 0; g < 4; ++g)
        acc[1][g] = __builtin_amdgcn_mfma_f32_16x16x32_bf16(af1[kt], bfr[g][kt], acc[1][g], 0,0,0);
    ELEM_P2(0, 1);
    ELEM_P2(1, 0); ELEM_P2(1, 1);
    __syncthreads();
  }
  // hF in sm.h[0]

  // ================= MLP =================
  {
    bf16x8 af[2][4];
    #pragma unroll
    for (int G = 0; G < 2; ++G)
      #pragma unroll
      for (int kt = 0; kt < 4; ++kt)
        af[G][kt] = *(const bf16x8*)&sm.h[0][(G*16 + cc)*KPAD + kt*32 + qd*8];
    f32x4 a1[2][2];
    #pragma unroll
    for (int t2 = 0; t2 < 2; ++t2){
      const int n = jq*32 + t2*16 + cc;
      float b = bm1[n];
      #pragma unroll
      for (int G = 0; G < 2; ++G){ a1[t2][G][0]=b; a1[t2][G][1]=b; a1[t2][G][2]=b; a1[t2][G][3]=b; }
      #pragma unroll
      for (int kt = 0; kt < 4; ++kt){
        bf16x8 wb = pack8(Wm1 + (size_t)n * HID + kt*32 + qd*8);
        a1[t2][0] = __builtin_amdgcn_mfma_f32_16x16x32_bf16(af[0][kt], wb, a1[t2][0], 0,0,0);
        a1[t2][1] = __builtin_amdgcn_mfma_f32_16x16x32_bf16(af[1][kt], wb, a1[t2][1], 0,0,0);
      }
    }
    __syncthreads();
    #pragma unroll
    for (int t2 = 0; t2 < 2; ++t2)
      #pragma unroll
      for (int G = 0; G < 2; ++G)
        #pragma unroll
        for (int r = 0; r < 4; ++r){
          float v = a1[t2][G][r]; v = v > 0.f ? v : 0.f;
          sm.u.h1[(G*16 + qd*4 + r)*H1PAD + jq*32 + t2*16 + cc] = bfs(v);
        }
  }
  __syncthreads();
  {
    bf16x8 af2[2][8];
    #pragma unroll
    for (int G = 0; G < 2; ++G)
      #pragma unroll
      for (int kt = 0; kt < 8; ++kt)
        af2[G][kt] = *(const bf16x8*)&sm.u.h1[(G*16 + cc)*H1PAD + kt*32 + qd*8];
    if (jq < 7){
      const int n2 = jq*16 + cc;
      float b = bm2[n2];
      f32x4 a2[2];
      #pragma unroll
      for (int G = 0; G < 2; ++G){ a2[G][0]=b; a2[G][1]=b; a2[G][2]=b; a2[G][3]=b; }
      #pragma unroll
      for (int kt = 0; kt < 8; ++kt){
        bf16x8 wb = pack8(Wm2 + (size_t)n2 * MD + kt*32 + qd*8);
        a2[0] = __builtin_amdgcn_mfma_f32_16x16x32_bf16(af2[0][kt], wb, a2[0], 0,0,0);
        a2[1] = __builtin_amdgcn_mfma_f32_16x16x32_bf16(af2[1][kt], wb, a2[1], 0,0,0);
      }
      #pragma unroll
      for (int G = 0; G < 2; ++G)
        #pragma unroll
        for (int r = 0; r < 4; ++r){
          float v = a2[G][r]; v = v > 0.f ? v : 0.f;
          sm.h[0][(G*16 + qd*4 + r)*KPAD + jq*16 + cc] = bfs(v);
        }
    }
    {
      int row = tid >> 4, nz = tid & 15;
      sm.h[0][row*KPAD + M2N + nz] = bfs(z[(size_t)(R0 + row)*NZ + nz]);
    }
  }
  __syncthreads();   // dh complete in h[0]

  // ================= decoder prep =================
  {
    const float* wr = Wih_d + tid * EMB;
    float w0 = 0.f, w1 = 0.f, bb = b_d[tid];
    for (int e = 0; e < EMB; ++e){
      float w = wr[e];
      w0 += w * Wd[e*2]; w1 += w * Wd[e*2+1]; bb += w * bd[e];
    }
    sm.u.cl[tid] = make_float4(bb, w0, w1, 0.f);
  }
  const float br0 = br[0], br1 = br[1];
  const float brc = (cc == 0) ? br0 : br1;
  if (jq == 1){   // readout Wr fragments + step-0 delta (one-time)
    uint4 bq[4];
    #pragma unroll
    for (int kt = 0; kt < 4; ++kt){
      bf16x8 f = pack8(Wr + (size_t)(cc & 1)*HID + kt*32 + qd*8);
      uint4 uu = __builtin_bit_cast(uint4, f);
      if (cc >= 2){ uu.x = 0u; uu.y = 0u; uu.z = 0u; uu.w = 0u; }
      bq[kt] = uu;
      sm.b5f[lane][kt] = uu;
    }
    #pragma unroll
    for (int G = 0; G < 2; ++G){
      bf16x8 afd[4];
      #pragma unroll
      for (int kt = 0; kt < 4; ++kt)
        afd[kt] = *(const bf16x8*)&sm.h[0][(G*16 + cc)*KPAD + kt*32 + qd*8];
      f32x4 a5 = zz4;
      #pragma unroll
      for (int kt = 0; kt < 4; ++kt)
        a5 = __builtin_amdgcn_mfma_f32_16x16x32_bf16(afd[kt], __builtin_bit_cast(bf16x8, bq[kt]), a5, 0,0,0);
      if (cc < 2){
        #pragma unroll
        for (int r = 0; r < 4; ++r){
          int row = G*16 + qd*4 + r;
          sm.delta[row][cc] = sm.offlast[row][cc] - (a5[r] + brc);
        }
      }
    }
  }
  __syncthreads();

  // feedback-folded decoder consts (pre-scaled): bfr' = s_g*(Whh_d + u0(x)Wr0 + u1(x)Wr1)
  float w0g[4], w1g[4];
  f32x4 civ[4];                 // steady-state C-init: splat(s_g * bc'_g)
  #pragma unroll
  for (int g = 0; g < 4; ++g){
    float4 v = sm.u.cl[g*128 + colj];
    w0g[g] = v.y; w1g[g] = v.z;
    float s = sg4[g];
    float bcp = v.x + v.y*br0 + v.z*br1;
    float ci = s * bcp;
    civ[g][0] = ci; civ[g][1] = ci; civ[g][2] = ci; civ[g][3] = ci;
    uint4 w;
    w.x = q0 ? pkbf(s*v.y, s*v.z) : 0u;
    w.y = q0 ? (rnd16(s*bcp) >> 16) : 0u;
    w.z = 0u; w.w = 0u;
    b5x[g] = __builtin_bit_cast(bf16x8, w);
  }
  #pragma unroll
  for (int kt = 0; kt < 4; ++kt){
    const int kb = kt*32 + qd*8;
    float4 wa = *(const float4*)(Wr + kb),       wb2 = *(const float4*)(Wr + kb + 4);
    float4 va = *(const float4*)(Wr + HID + kb), vb2 = *(const float4*)(Wr + HID + kb + 4);
    #pragma unroll
    for (int g = 0; g < 4; ++g){
      const float* pp = Whh_d + (size_t)(g*128 + colj) * HID + kb;
      float4 fa = *(const float4*)pp, fb = *(const float4*)(pp + 4);
      float s = sg4[g];
      uint4 uu;
      uu.x = pkbf(s*(fa.x + w0g[g]*wa.x  + w1g[g]*va.x),  s*(fa.y + w0g[g]*wa.y  + w1g[g]*va.y));
      uu.y = pkbf(s*(fa.z + w0g[g]*wa.z  + w1g[g]*va.z),  s*(fa.w + w0g[g]*wa.w  + w1g[g]*va.w));
      uu.z = pkbf(s*(fb.x + w0g[g]*wb2.x + w1g[g]*vb2.x), s*(fb.y + w0g[g]*wb2.y + w1g[g]*vb2.y));
      uu.w = pkbf(s*(fb.z + w0g[g]*wb2.z + w1g[g]*vb2.z), s*(fb.w + w0g[g]*wb2.w + w1g[g]*vb2.w));
      bfr[g][kt] = __builtin_bit_cast(bf16x8, uu);
    }
  }
  // step-0 delta A-frags
  uint4 c5; c5.x = 0u; c5.y = one_q0; c5.z = 0u; c5.w = 0u;
  float2 dv0 = *(const float2*)&sm.delta[cc][0];
  float2 dv1 = *(const float2*)&sm.delta[16 + cc][0];
  uint4 d0u = c5; d0u.x = q0 ? pkbf(dv0.x, dv0.y) : 0u;
  uint4 d1u = c5; d1u.x = q0 ? pkbf(dv1.x, dv1.y) : 0u;
  const bf16x8 af5d0 = __builtin_bit_cast(bf16x8, d0u);
  const bf16x8 af5d1 = __builtin_bit_cast(bf16x8, d1u);

  // readout ownership: jq==1 -> G0 rows, jq==3 -> G1 rows
  const int Gown = (jq == 3) ? 1 : 0;
  float cum[4] = {0.f,0.f,0.f,0.f};
  if ((jq == 1 || jq == 3) && cc < 2){
    #pragma unroll
    for (int r = 0; r < 4; ++r)
      cum[r] = obs[(size_t)(R0 + Gown*16 + qd*4 + r)*(TOBS*2) + (TOBS-1)*2 + cc];
  }
  #pragma unroll
  for (int G = 0; G < 2; ++G)
    #pragma unroll
    for (int r = 0; r < 4; ++r) cst[G][r] = 0.f;
  __syncthreads();   // cl reads done; outst region now writable

  // ================= decoder: 100 steps, ONE barrier/step, NO global ops =================
  #pragma unroll 1
  for (int s = 0; s < SDEC; ++s){
    const int par = s & 1;
    bf16x8 af0[4], af1[4];
    #pragma unroll
    for (int kt = 0; kt < 4; ++kt)
      af0[kt] = *(const bf16x8*)&sm.h[par][cc*KPAD + kt*32 + qd*8];
    // G0 chain (kt0 carries the C-init; s==0 adds the delta-MFMA)
    if (s == 0){
      #pragma unroll
      for (int g = 0; g < 4; ++g){
        acc[0][g] = __builtin_amdgcn_mfma_f32_16x16x32_bf16(af5d0, b5x[g], zz4, 0,0,0);
        acc[0][g] = __builtin_amdgcn_mfma_f32_16x16x32_bf16(af0[0], bfr[g][0], acc[0][g], 0,0,0);
      }
    } else {
      #pragma unroll
      for (int g = 0; g < 4; ++g)
        acc[0][g] = __builtin_amdgcn_mfma_f32_16x16x32_bf16(af0[0], bfr[g][0], civ[g], 0,0,0);
    }
    #pragma unroll
    for (int kt = 1; kt < 4; ++kt)
      #pragma unroll
      for (int g = 0; g < 4; ++g)
        acc[0][g] = __builtin_amdgcn_mfma_f32_16x16x32_bf16(af0[kt], bfr[g][kt], acc[0][g], 0,0,0);
    #pragma unroll
    for (int kt = 0; kt < 4; ++kt)
      af1[kt] = *(const bf16x8*)&sm.h[par][(16 + cc)*KPAD + kt*32 + qd*8];
    // readout G0 (wave jq==1 only)
    if (jq == 1 && s > 0){
      f32x4 a5 = {brc, brc, brc, brc};
      #pragma unroll
      for (int kt = 0; kt < 4; ++kt)
        a5 = __builtin_amdgcn_mfma_f32_16x16x32_bf16(af0[kt],
               __builtin_bit_cast(bf16x8, sm.b5f[lane][kt]), a5, 0,0,0);
      if (cc < 2){
        #pragma unroll
        for (int r = 0; r < 4; ++r){
          cum[r] += a5[r];
          sm.u.outst[qd*4 + r][s-1][cc] = cum[r];
        }
      }
    }
    // G1 chain interleaved with G0 ELEM pairs
    unsigned short* hn = &sm.h[par ^ 1][0];
    if (s == 0){
      #pragma unroll
      for (int g = 0; g < 4; ++g){
        acc[1][g] = __builtin_amdgcn_mfma_f32_16x16x32_bf16(af5d1, b5x[g], zz4, 0,0,0);
        acc[1][g] = __builtin_amdgcn_mfma_f32_16x16x32_bf16(af1[0], bfr[g][0], acc[1][g], 0,0,0);
      }
    } else {
      #pragma unroll
      for (int g = 0; g < 4; ++g)
        acc[1][g] = __builtin_amdgcn_mfma_f32_16x16x32_bf16(af1[0], bfr[g][0], civ[g], 0,0,0);
    }
    #pragma unroll
    for (int g = 0; g < 4; ++g)
      acc[1][g] = __builtin_amdgcn_mfma_f32_16x16x32_bf16(af1[1], bfr[g][1], acc[1][g], 0,0,0);
    ELEM_P2(0, 0);
    #pragma unroll
    for (int kt = 2; kt < 4; ++kt)
      #pragma unroll
      for (int g = 0; g < 4; ++g)
        acc[1][g] = __builtin_amdgcn_mfma_f32_16x16x32_bf16(af1[kt], bfr[g][kt], acc[1][g], 0,0,0);
    ELEM_P2(0, 1);
    // readout G1 (wave jq==3 only) — matrix work overlapping others' ELEM
    if (jq == 3 && s > 0){
      f32x4 a5 = {brc, brc, brc, brc};
      #pragma unroll
      for (int kt = 0; kt < 4; ++kt)
        a5 = __builtin_amdgcn_mfma_f32_16x16x32_bf16(af1[kt],
               __builtin_bit_cast(bf16x8, sm.b5f[lane][kt]), a5, 0,0,0);
      if (cc < 2){
        #pragma unroll
        for (int r = 0; r < 4; ++r){
          cum[r] += a5[r];
          sm.u.outst[16 + qd*4 + r][s-1][cc] = cum[r];
        }
      }
    }
    ELEM_P2(1, 0); ELEM_P2(1, 1);
    __syncthreads();
  }

  // epilogue: pred[S-1] from h[0] (= h_{S-1}); split across jq==1 / jq==3
  if (jq == 1 || jq == 3){
    bf16x8 af[4];
    #pragma unroll
    for (int kt = 0; kt < 4; ++kt)
      af[kt] = *(const bf16x8*)&sm.h[0][(Gown*16 + cc)*KPAD + kt*32 + qd*8];
    f32x4 a5 = {brc, brc, brc, brc};
    #pragma unroll
    for (int kt = 0; kt < 4; ++kt)
      a5 = __builtin_amdgcn_mfma_f32_16x16x32_bf16(af[kt],
             __builtin_bit_cast(bf16x8, sm.b5f[lane][kt]), a5, 0,0,0);
    if (cc < 2){
      #pragma unroll
      for (int r = 0; r < 4; ++r)
        sm.u.outst[Gown*16 + qd*4 + r][SDEC-1][cc] = cum[r] + a5[r];
    }
  }
  __syncthreads();

  // bulk write: LDS staging -> HBM, fully coalesced float2
  {
    const float2* src = (const float2*)&sm.u.outst[0][0][0];
    float2* dst = (float2*)(out + (size_t)R0 * SDEC * 2);
    for (int i = tid; i < ROWS * SDEC; i += 512)
      dst[i] = src[i];
  }
}

extern "C" void kernel_launch(void* const* d_in, const int* in_sizes, int n_in,
                              void* d_out, int out_size, void* d_ws, size_t ws_size,
                              hipStream_t stream) {
  (void)in_sizes; (void)n_in; (void)d_ws; (void)ws_size; (void)out_size;
  const float* obs   = (const float*)d_in[0];
  // d_in[1] = num_steps (100), compile-time constant here
  const float* We    = (const float*)d_in[2];
  const float* be    = (const float*)d_in[3];
  const float* Wih_e = (const float*)d_in[4];
  const float* Whh_e = (const float*)d_in[5];
  const float* b_e   = (const float*)d_in[6];
  const float* Wm1   = (const float*)d_in[7];
  const float* bm1   = (const float*)d_in[8];
  const float* Wm2   = (const float*)d_in[9];
  const float* bm2   = (const float*)d_in[10];
  const float* Wd    = (const float*)d_in[11];
  const float* bd    = (const float*)d_in[12];
  const float* Wih_d = (const float*)d_in[13];
  const float* Whh_d = (const float*)d_in[14];
  const float* b_d   = (const float*)d_in[15];
  const float* Wr    = (const float*)d_in[16];
  const float* br    = (const float*)d_in[17];
  const float* zz    = (const float*)d_in[18];
  hipLaunchKernelGGL(seqgen, dim3(8192 / ROWS), dim3(512), 0, stream,
                     obs, We, be, Wih_e, Whh_e, b_e, Wm1, bm1, Wm2, bm2,
                     Wd, bd, Wih_d, Whh_d, b_d, Wr, br, zz, (float*)d_out);
}